// Round 7
// baseline (68.584 us; speedup 1.0000x reference)
//
#include <hip/hip_runtime.h>
#include <stdint.h>

#define D_M   1024
#define L_OBS 2048
#define ALPHA 8192
#define D_H   2048

typedef __attribute__((ext_vector_type(8))) short short8;
typedef __attribute__((ext_vector_type(4))) float f32x4;

__device__ inline unsigned short f2bf(float f) {
  union { float f; unsigned u; } c; c.f = f;
  unsigned u = c.u;
  u += 0x7fffu + ((u >> 16) & 1u);   // round-to-nearest-even
  return (unsigned short)(u >> 16);
}

// ---------------- Kernel 1: scatter + forward-fill, one row per block --------
__global__ __launch_bounds__(1024) void impute_fill(
    const float* __restrict__ x_ts, const int* __restrict__ t_ts,
    const float* __restrict__ gmean, unsigned short* __restrict__ dst,
    int transposed_out) {
  __shared__ unsigned long long pack[ALPHA];   // 64 KB; 0 = no observation
  __shared__ float s_wv[16];
  __shared__ int   s_wh[16];

  const int m    = blockIdx.x;
  const int tid  = threadIdx.x;
  const int lane = tid & 63;
  const int wv   = tid >> 6;

  #pragma unroll
  for (int i = 0; i < 8; ++i) pack[tid + i * 1024] = 0ull;
  __syncthreads();

  #pragma unroll
  for (int j = 0; j < 2; ++j) {
    const int l = tid + j * 1024;
    const float xv = x_ts[(size_t)m * L_OBS + l];
    const int   tv = t_ts[(size_t)m * L_OBS + l];
    if ((xv == xv) && (tv >= 0) && (tv < ALPHA)) {
      union { float f; unsigned u; } c; c.f = xv;
      atomicMax(&pack[tv], ((unsigned long long)(l + 1) << 32) | c.u);
    }
  }
  __syncthreads();

  const int base = tid * 8;
  int has = 0; float lv = 0.f;
  #pragma unroll
  for (int i = 0; i < 8; ++i) {
    const unsigned long long p = pack[base + i];
    if (p >> 32) { has = 1; lv = __uint_as_float((unsigned)p); }
  }

  int ihas = has; float ilv = lv;
  #pragma unroll
  for (int d = 1; d < 64; d <<= 1) {
    const float pv = __shfl_up(ilv, d, 64);
    const int   ph = __shfl_up(ihas, d, 64);
    if (lane >= d && !ihas) { ihas = ph; ilv = pv; }
  }
  if (lane == 63) { s_wh[wv] = ihas; s_wv[wv] = ilv; }
  __syncthreads();
  if (wv == 0 && lane < 16) {
    int h2 = s_wh[lane]; float v2 = s_wv[lane];
    #pragma unroll
    for (int d = 1; d < 16; d <<= 1) {
      const float pv = __shfl_up(v2, d, 16);
      const int   ph = __shfl_up(h2, d, 16);
      if (lane >= d && !h2) { h2 = ph; v2 = pv; }
    }
    s_wh[lane] = h2; s_wv[lane] = v2;
  }
  __syncthreads();

  const float xlv = __shfl_up(ilv, 1, 64);
  const int   xh_ = __shfl_up(ihas, 1, 64);
  const int   xhas = (lane > 0) ? xh_ : 0;
  float running;
  if (xhas)                         running = xlv;
  else if (wv > 0 && s_wh[wv - 1])  running = s_wv[wv - 1];
  else                              running = gmean[m];

  if (transposed_out) {
    #pragma unroll
    for (int i = 0; i < 8; ++i) {
      const unsigned long long p = pack[base + i];
      if (p >> 32) running = __uint_as_float((unsigned)p);
      dst[(size_t)(base + i) * D_M + m] = f2bf(running);
    }
  } else {
    short8 ov;
    #pragma unroll
    for (int i = 0; i < 8; ++i) {
      const unsigned long long p = pack[base + i];
      if (p >> 32) running = __uint_as_float((unsigned)p);
      ov[i] = (short)f2bf(running);
    }
    *(short8*)&dst[(size_t)m * ALPHA + base] = ov;
  }
}

// ---------------- Kernel 1b: transpose reg[m][a] -> regT[a][m] ---------------
__global__ __launch_bounds__(256) void transpose_bf(
    const unsigned short* __restrict__ reg, unsigned short* __restrict__ regT) {
  __shared__ unsigned short tile[64 * 64];
  const int t  = threadIdx.x;
  const int m0 = (blockIdx.x & 15) * 64;
  const int A0 = (blockIdx.x >> 4) * 64;

  #pragma unroll
  for (int i = 0; i < 2; ++i) {
    const int m  = i * 32 + (t >> 3);
    const int ao = (t & 7) * 8;
    short8 v = *(const short8*)&reg[(size_t)(m0 + m) * ALPHA + A0 + ao];
    const int s = ((m & 7) ^ (m >> 3)) << 3;
    *(short8*)&tile[m * 64 + (ao ^ s)] = v;
  }
  __syncthreads();
  #pragma unroll
  for (int i = 0; i < 2; ++i) {
    const int a  = i * 32 + (t >> 3);
    const int mo = (t & 7) * 8;
    short8 ov;
    #pragma unroll
    for (int j = 0; j < 8; ++j) {
      const int mm = mo + j;
      const int s  = ((mm & 7) ^ (mm >> 3)) << 3;
      ov[j] = (short)tile[mm * 64 + (a ^ s)];
    }
    *(short8*)&regT[(size_t)(A0 + a) * D_M + m0 + mo] = ov;
  }
}

// ---------------- Kernel 2: W f32 -> bf16 ------------------------------------
__global__ __launch_bounds__(256) void wconv(const float* __restrict__ W,
                                             unsigned short* __restrict__ Wb) {
  const int i = (blockIdx.x * 256 + threadIdx.x) * 4;
  const float4 w = *reinterpret_cast<const float4*>(&W[i]);
  ushort4 o;
  o.x = f2bf(w.x); o.y = f2bf(w.y); o.z = f2bf(w.z); o.w = f2bf(w.w);
  *reinterpret_cast<ushort4*>(&Wb[i]) = o;
}

// ---------------- Kernel 3: 256x256 GEMM, fragment-pipelined 4-phase ---------
// out[a][h] = sum_m regT[a][m] * Wb[h][m] + b[h];  M=8192 N=2048 K=1024.
// BK=64 -> 16 K-tiles; per tile 4 phases x 16 MFMA. KEY: MFMA(p) consumes
// fragments ds_read at p-1 (a0/a1 ping-pong per 2 phases, b0/b1 per phase;
// roles return to identity after 4 phases -> static names, no dyn indexing).
// Each phase: lgkm0 (confirm prev reads; also cross-wave overwrite safety)
// -> 6 balanced ds_reads for NEXT phase + 1 half stage -> 16 MFMA.
// LDS ring: A slots 0..3 @ s*16K, B @ 64K + s*16K (128 KB). Swizzle = R4's
// 0-conflict pair. vmcnt(6) at end of P0/P2 (3 halves in flight); audited:
// every read's half landed; every slot overwrite >=1 barrier after readers'
// lgkm0. Tail ladder 6 -> 2 -> 0.
#define GNT 16

__device__ inline void gload_lds16(const void* g, void* l) {
  __builtin_amdgcn_global_load_lds(
      (const __attribute__((address_space(1))) unsigned int*)g,
      (__attribute__((address_space(3))) unsigned int*)l, 16, 0, 0);
}

#define BARX() { asm volatile("" ::: "memory"); __builtin_amdgcn_s_barrier(); \
                 asm volatile("" ::: "memory"); }
#define LGKM0() asm volatile("s_waitcnt lgkmcnt(0)" ::: "memory")
#define SB0()   __builtin_amdgcn_sched_barrier(0)

__global__ __launch_bounds__(512, 2) void gemm_bias(
    const unsigned short* __restrict__ A,   // regT [ALPHA][D_M]
    const unsigned short* __restrict__ B,   // Wb   [D_H][D_M]
    const float* __restrict__ bias, float* __restrict__ out) {
  __shared__ char lds[131072];

  const int tid  = threadIdx.x;
  const int lane = tid & 63;
  const int wid  = tid >> 6;
  const int wm   = wid >> 2;                // 0..1  (m-half of C)
  const int wn   = wid & 3;                 // 0..3  (n-quarter of C)
  const int bn   = blockIdx.x & 7;          // bid%8 = XCD -> B panel L2-local
  const int bm   = blockIdx.x >> 3;
  const int a0r = bm * 256, h0 = bn * 256;

  f32x4 acc[8][4] = {};
  short8 a0[8], a1[8], b0[2], b1[2];

  // ---- staging: linear LDS dest (tid*16), inverse-swizzled global source
  const int r0 = tid >> 2, s0 = tid & 3;
  const int swzB = (s0 ^ ((r0 >> 1) & 3)) * 16;        // R4 form: 0 conflicts
  const char* Asrc0 = (const char*)A + ((size_t)(a0r + r0) * D_M) * 2 + swzB;
  const char* Asrc1 = Asrc0 + (size_t)128 * D_M * 2;
  const char* Bsrc0 = (const char*)B + ((size_t)(h0 + r0) * D_M) * 2 + swzB;
  const char* Bsrc1 = Bsrc0 + (size_t)128 * D_M * 2;

#define STAGE_A_S(S, kh) { char* d_ = lds + (S) * 16384 + tid * 16; \
  gload_lds16(Asrc0 + (size_t)(kh) * 64, d_); \
  gload_lds16(Asrc1 + (size_t)(kh) * 64, d_ + 8192); }
#define STAGE_B_S(S, kh) { char* d_ = lds + 65536 + (S) * 16384 + tid * 16; \
  gload_lds16(Bsrc0 + (size_t)(kh) * 64, d_); \
  gload_lds16(Bsrc1 + (size_t)(kh) * 64, d_ + 8192); }

  // ---- fragment read offsets (same involutive swizzle, R4 form)
  const int rl  = lane & 15;
  const int rsw = (((lane >> 4) ^ ((rl >> 1) & 3))) * 16;
  const int Aro = (wm * 128 + rl) * 64 + rsw;           // + mf*1024 + slot*16K
  const int Bro = 65536 + (wn * 64 + rl) * 64 + rsw;    // + n*1024  + slot*16K

#define LDA(S, mf) (*(const short8*)(lds + (S) * 16384 + Aro + (mf) * 1024))
#define LDB(S, n)  (*(const short8*)(lds + (S) * 16384 + Bro + (n) * 1024))

#define MFMA16(AF, BF, N0, N1) \
  __builtin_amdgcn_s_setprio(1); \
  _Pragma("unroll") \
  for (int mf = 0; mf < 8; ++mf) { \
    acc[mf][N0] = __builtin_amdgcn_mfma_f32_16x16x32_bf16(AF[mf], BF[0], acc[mf][N0], 0, 0, 0); \
    acc[mf][N1] = __builtin_amdgcn_mfma_f32_16x16x32_bf16(AF[mf], BF[1], acc[mf][N1], 0, 0, 0); \
  } \
  __builtin_amdgcn_s_setprio(0);

  // Steady tile: S0..S3 = slots of kh0..kh0+3 (mod 4); KH0 = 2t.
#define TILE(S0, S1, S2, S3, KH0) { \
  /* P0: use a0 x b0 -> acc[:][0,1]; read b1=B(kh0,n23), a1[0:4]=A(kh1) */ \
  LGKM0(); SB0(); \
  b1[0] = LDB(S0, 2); b1[1] = LDB(S0, 3); \
  a1[0] = LDA(S1, 0); a1[1] = LDA(S1, 1); a1[2] = LDA(S1, 2); a1[3] = LDA(S1, 3); \
  STAGE_B_S(S3, (KH0) + 3); \
  SB0(); \
  MFMA16(a0, b0, 0, 1); \
  asm volatile("s_waitcnt vmcnt(6)" ::: "memory"); \
  BARX(); \
  /* P1: use a0 x b1 -> acc[:][2,3]; read a1[4:8], b0=B(kh1,n01) */ \
  LGKM0(); SB0(); \
  a1[4] = LDA(S1, 4); a1[5] = LDA(S1, 5); a1[6] = LDA(S1, 6); a1[7] = LDA(S1, 7); \
  b0[0] = LDB(S1, 0); b0[1] = LDB(S1, 1); \
  STAGE_A_S(S0, (KH0) + 4); \
  SB0(); \
  MFMA16(a0, b1, 2, 3); \
  BARX(); \
  /* P2: use a1 x b0 -> acc[:][0,1]; read b1=B(kh1,n23), a0[0:4]=A(kh0+2) */ \
  LGKM0(); SB0(); \
  b1[0] = LDB(S1, 2); b1[1] = LDB(S1, 3); \
  a0[0] = LDA(S2, 0); a0[1] = LDA(S2, 1); a0[2] = LDA(S2, 2); a0[3] = LDA(S2, 3); \
  STAGE_B_S(S0, (KH0) + 4); \
  SB0(); \
  MFMA16(a1, b0, 0, 1); \
  asm volatile("s_waitcnt vmcnt(6)" ::: "memory"); \
  BARX(); \
  /* P3: use a1 x b1 -> acc[:][2,3]; read a0[4:8], b0=B(kh0+2,n01) */ \
  LGKM0(); SB0(); \
  a0[4] = LDA(S2, 4); a0[5] = LDA(S2, 5); a0[6] = LDA(S2, 6); a0[7] = LDA(S2, 7); \
  b0[0] = LDB(S2, 0); b0[1] = LDB(S2, 1); \
  STAGE_A_S(S1, (KH0) + 5); \
  SB0(); \
  MFMA16(a1, b1, 2, 3); \
  BARX(); \
}

  // ---- prologue: 7 halves staged; kh0/kh1 landed; prime a0=A(0), b0=B(0,n01)
  STAGE_A_S(0, 0); STAGE_B_S(0, 0); STAGE_A_S(1, 1); STAGE_B_S(1, 1);
  STAGE_A_S(2, 2); STAGE_B_S(2, 2); STAGE_A_S(3, 3);
  asm volatile("s_waitcnt vmcnt(6)" ::: "memory");
  BARX();
  a0[0] = LDA(0, 0); a0[1] = LDA(0, 1); a0[2] = LDA(0, 2); a0[3] = LDA(0, 3);
  a0[4] = LDA(0, 4); a0[5] = LDA(0, 5); a0[6] = LDA(0, 6); a0[7] = LDA(0, 7);
  b0[0] = LDB(0, 0); b0[1] = LDB(0, 1);

  // ---- steady: t = 0..13 (stages reach kh=31 exactly)
  for (int tt = 0; tt < 7; ++tt) {
    const int k0 = 4 * tt;
    TILE(0, 1, 2, 3, k0);
    TILE(2, 3, 0, 1, k0 + 2);
  }

  // ---- tail t=14 (kh 28,29; stage only B31); vmcnt 6 -> 2
  LGKM0(); SB0();
  b1[0] = LDB(0, 2); b1[1] = LDB(0, 3);
  a1[0] = LDA(1, 0); a1[1] = LDA(1, 1); a1[2] = LDA(1, 2); a1[3] = LDA(1, 3);
  STAGE_B_S(3, 31);
  SB0(); MFMA16(a0, b0, 0, 1);
  asm volatile("s_waitcnt vmcnt(6)" ::: "memory");
  BARX();
  LGKM0(); SB0();
  a1[4] = LDA(1, 4); a1[5] = LDA(1, 5); a1[6] = LDA(1, 6); a1[7] = LDA(1, 7);
  b0[0] = LDB(1, 0); b0[1] = LDB(1, 1);
  SB0(); MFMA16(a0, b1, 2, 3);
  BARX();
  LGKM0(); SB0();
  b1[0] = LDB(1, 2); b1[1] = LDB(1, 3);
  a0[0] = LDA(2, 0); a0[1] = LDA(2, 1); a0[2] = LDA(2, 2); a0[3] = LDA(2, 3);
  SB0(); MFMA16(a1, b0, 0, 1);
  asm volatile("s_waitcnt vmcnt(2)" ::: "memory");   // only B31 may remain
  BARX();
  LGKM0(); SB0();
  a0[4] = LDA(2, 4); a0[5] = LDA(2, 5); a0[6] = LDA(2, 6); a0[7] = LDA(2, 7);
  b0[0] = LDB(2, 0); b0[1] = LDB(2, 1);
  SB0(); MFMA16(a1, b1, 2, 3);
  BARX();
  // ---- tail t=15 (kh 30,31; no staging)
  LGKM0(); SB0();
  b1[0] = LDB(2, 2); b1[1] = LDB(2, 3);
  a1[0] = LDA(3, 0); a1[1] = LDA(3, 1); a1[2] = LDA(3, 2); a1[3] = LDA(3, 3);
  SB0(); MFMA16(a0, b0, 0, 1);
  asm volatile("s_waitcnt vmcnt(0)" ::: "memory");
  BARX();
  LGKM0(); SB0();
  a1[4] = LDA(3, 4); a1[5] = LDA(3, 5); a1[6] = LDA(3, 6); a1[7] = LDA(3, 7);
  b0[0] = LDB(3, 0); b0[1] = LDB(3, 1);
  SB0(); MFMA16(a0, b1, 2, 3);
  BARX();
  LGKM0(); SB0();
  b1[0] = LDB(3, 2); b1[1] = LDB(3, 3);
  SB0(); MFMA16(a1, b0, 0, 1);
  BARX();
  LGKM0(); SB0();
  MFMA16(a1, b1, 2, 3);

  // ---- epilogue: C row = (lane>>4)*4 + r (A side), col = lane&15 (B side)
  const int cl = lane & 15, rq = lane >> 4;
  #pragma unroll
  for (int n = 0; n < 4; ++n) {
    const int h = h0 + wn * 64 + n * 16 + cl;
    const float bv = bias[h];
    #pragma unroll
    for (int f = 0; f < 8; ++f) {
      const int ar = a0r + wm * 128 + f * 16 + rq * 4;
      #pragma unroll
      for (int r = 0; r < 4; ++r)
        out[(size_t)(ar + r) * D_H + h] = acc[f][n][r] + bv;
    }
  }
#undef STAGE_A_S
#undef STAGE_B_S
#undef LDA
#undef LDB
#undef MFMA16
#undef TILE
}

extern "C" void kernel_launch(void* const* d_in, const int* in_sizes, int n_in,
                              void* d_out, int out_size, void* d_ws, size_t ws_size,
                              hipStream_t stream) {
  const float* x  = (const float*)d_in[0];
  const int*   t  = (const int*)d_in[1];
  const float* gm = (const float*)d_in[2];
  const float* W  = (const float*)d_in[3];
  const float* b  = (const float*)d_in[4];
  float* out = (float*)d_out;

  const size_t SZ_REG = (size_t)ALPHA * D_M * 2;   // 16 MB
  const size_t SZ_WB  = (size_t)D_H * D_M * 2;     //  4 MB

  if (ws_size >= 2 * SZ_REG + SZ_WB) {
    unsigned short* reg  = (unsigned short*)d_ws;
    unsigned short* regT = (unsigned short*)((char*)d_ws + SZ_REG);
    unsigned short* Wb   = (unsigned short*)((char*)d_ws + 2 * SZ_REG);
    impute_fill<<<D_M, 1024, 0, stream>>>(x, t, gm, reg, 0);
    wconv<<<(D_H * D_M) / 1024, 256, 0, stream>>>(W, Wb);
    transpose_bf<<<(ALPHA / 64) * (D_M / 64), 256, 0, stream>>>(reg, regT);
    gemm_bias<<<(ALPHA / 256) * (D_H / 256), 512, 0, stream>>>(regT, Wb, b, out);
  } else {
    unsigned short* regT = (unsigned short*)d_ws;
    unsigned short* Wb   = (unsigned short*)((char*)d_ws + SZ_REG);
    impute_fill<<<D_M, 1024, 0, stream>>>(x, t, gm, regT, 1);
    wconv<<<(D_H * D_M) / 1024, 256, 0, stream>>>(W, Wb);
    gemm_bias<<<(ALPHA / 256) * (D_H / 256), 512, 0, stream>>>(regT, Wb, b, out);
  }
}

// Round 8
// 67.868 us; speedup vs baseline: 1.0105x; 1.0105x over previous
//
#include <hip/hip_runtime.h>
#include <stdint.h>

#define D_M   1024
#define L_OBS 2048
#define ALPHA 8192
#define D_H   2048

typedef __attribute__((ext_vector_type(8))) short short8;
typedef __attribute__((ext_vector_type(4))) float f32x4;

__device__ inline unsigned short f2bf(float f) {
  union { float f; unsigned u; } c; c.f = f;
  unsigned u = c.u;
  u += 0x7fffu + ((u >> 16) & 1u);   // round-to-nearest-even
  return (unsigned short)(u >> 16);
}

// ---------------- Kernel 1: scatter + forward-fill, one row per block --------
__global__ __launch_bounds__(1024) void impute_fill(
    const float* __restrict__ x_ts, const int* __restrict__ t_ts,
    const float* __restrict__ gmean, unsigned short* __restrict__ dst,
    int transposed_out) {
  __shared__ unsigned long long pack[ALPHA];   // 64 KB; 0 = no observation
  __shared__ float s_wv[16];
  __shared__ int   s_wh[16];

  const int m    = blockIdx.x;
  const int tid  = threadIdx.x;
  const int lane = tid & 63;
  const int wv   = tid >> 6;

  #pragma unroll
  for (int i = 0; i < 8; ++i) pack[tid + i * 1024] = 0ull;
  __syncthreads();

  #pragma unroll
  for (int j = 0; j < 2; ++j) {
    const int l = tid + j * 1024;
    const float xv = x_ts[(size_t)m * L_OBS + l];
    const int   tv = t_ts[(size_t)m * L_OBS + l];
    if ((xv == xv) && (tv >= 0) && (tv < ALPHA)) {
      union { float f; unsigned u; } c; c.f = xv;
      atomicMax(&pack[tv], ((unsigned long long)(l + 1) << 32) | c.u);
    }
  }
  __syncthreads();

  const int base = tid * 8;
  int has = 0; float lv = 0.f;
  #pragma unroll
  for (int i = 0; i < 8; ++i) {
    const unsigned long long p = pack[base + i];
    if (p >> 32) { has = 1; lv = __uint_as_float((unsigned)p); }
  }

  int ihas = has; float ilv = lv;
  #pragma unroll
  for (int d = 1; d < 64; d <<= 1) {
    const float pv = __shfl_up(ilv, d, 64);
    const int   ph = __shfl_up(ihas, d, 64);
    if (lane >= d && !ihas) { ihas = ph; ilv = pv; }
  }
  if (lane == 63) { s_wh[wv] = ihas; s_wv[wv] = ilv; }
  __syncthreads();
  if (wv == 0 && lane < 16) {
    int h2 = s_wh[lane]; float v2 = s_wv[lane];
    #pragma unroll
    for (int d = 1; d < 16; d <<= 1) {
      const float pv = __shfl_up(v2, d, 16);
      const int   ph = __shfl_up(h2, d, 16);
      if (lane >= d && !h2) { h2 = ph; v2 = pv; }
    }
    s_wh[lane] = h2; s_wv[lane] = v2;
  }
  __syncthreads();

  const float xlv = __shfl_up(ilv, 1, 64);
  const int   xh_ = __shfl_up(ihas, 1, 64);
  const int   xhas = (lane > 0) ? xh_ : 0;
  float running;
  if (xhas)                         running = xlv;
  else if (wv > 0 && s_wh[wv - 1])  running = s_wv[wv - 1];
  else                              running = gmean[m];

  if (transposed_out) {
    #pragma unroll
    for (int i = 0; i < 8; ++i) {
      const unsigned long long p = pack[base + i];
      if (p >> 32) running = __uint_as_float((unsigned)p);
      dst[(size_t)(base + i) * D_M + m] = f2bf(running);
    }
  } else {
    short8 ov;
    #pragma unroll
    for (int i = 0; i < 8; ++i) {
      const unsigned long long p = pack[base + i];
      if (p >> 32) running = __uint_as_float((unsigned)p);
      ov[i] = (short)f2bf(running);
    }
    *(short8*)&dst[(size_t)m * ALPHA + base] = ov;
  }
}

// ---------------- Kernel 1b: transpose reg[m][a] -> regT[a][m] ---------------
__global__ __launch_bounds__(256) void transpose_bf(
    const unsigned short* __restrict__ reg, unsigned short* __restrict__ regT) {
  __shared__ unsigned short tile[64 * 64];
  const int t  = threadIdx.x;
  const int m0 = (blockIdx.x & 15) * 64;
  const int A0 = (blockIdx.x >> 4) * 64;

  #pragma unroll
  for (int i = 0; i < 2; ++i) {
    const int m  = i * 32 + (t >> 3);
    const int ao = (t & 7) * 8;
    short8 v = *(const short8*)&reg[(size_t)(m0 + m) * ALPHA + A0 + ao];
    const int s = ((m & 7) ^ (m >> 3)) << 3;
    *(short8*)&tile[m * 64 + (ao ^ s)] = v;
  }
  __syncthreads();
  #pragma unroll
  for (int i = 0; i < 2; ++i) {
    const int a  = i * 32 + (t >> 3);
    const int mo = (t & 7) * 8;
    short8 ov;
    #pragma unroll
    for (int j = 0; j < 8; ++j) {
      const int mm = mo + j;
      const int s  = ((mm & 7) ^ (mm >> 3)) << 3;
      ov[j] = (short)tile[mm * 64 + (a ^ s)];
    }
    *(short8*)&regT[(size_t)(A0 + a) * D_M + m0 + mo] = ov;
  }
}

// ---------------- Kernel 2: W f32 -> bf16 ------------------------------------
__global__ __launch_bounds__(256) void wconv(const float* __restrict__ W,
                                             unsigned short* __restrict__ Wb) {
  const int i = (blockIdx.x * 256 + threadIdx.x) * 4;
  const float4 w = *reinterpret_cast<const float4*>(&W[i]);
  ushort4 o;
  o.x = f2bf(w.x); o.y = f2bf(w.y); o.z = f2bf(w.z); o.w = f2bf(w.w);
  *reinterpret_cast<ushort4*>(&Wb[i]) = o;
}

// ---------------- Kernel 3: 128x256 GEMM, 2 blocks/CU ------------------------
// out[a][h] = sum_m regT[a][m] * Wb[h][m] + b[h];  M=8192 N=2048 K=1024.
// CHANGE vs R4-R7 (all ~54us, MfmaUtil 25%, 1 block/CU): occupancy. Tile
// 128x256, grid 512 = 2 blocks/CU, LDS 72KB (3-slot BK=32 ring), lb(512,4)
// -> 4 waves/SIMD. Cross-block wave overlap hides per-phase lgkm/barrier
// stalls + epilogue writes (m114 mechanism); in-block schedule kept simple.
// 8 waves = 2M x 4N, per wave 64x64 (acc 4x4 f32x4 = 64 VGPR).
#define GNT3 32   // K-tiles (BK=32)

__device__ inline void gload_lds16(const void* g, void* l) {
  __builtin_amdgcn_global_load_lds(
      (const __attribute__((address_space(1))) unsigned int*)g,
      (__attribute__((address_space(3))) unsigned int*)l, 16, 0, 0);
}

#define BARX() { asm volatile("" ::: "memory"); __builtin_amdgcn_s_barrier(); \
                 asm volatile("" ::: "memory"); }
#define LGKM0() asm volatile("s_waitcnt lgkmcnt(0)" ::: "memory")
#define SB0()   __builtin_amdgcn_sched_barrier(0)

__global__ __launch_bounds__(512, 4) void gemm_bias(
    const unsigned short* __restrict__ A,   // regT [ALPHA][D_M]
    const unsigned short* __restrict__ B,   // Wb   [D_H][D_M]
    const float* __restrict__ bias, float* __restrict__ out) {
  __shared__ char lds[73728];               // A: 3 x 8KB @0; B: 3 x 16KB @24576

  const int tid  = threadIdx.x;
  const int lane = tid & 63;
  const int wid  = tid >> 6;
  const int wm   = wid >> 2;                // 0..1  (64-row half of 128)
  const int wn   = wid & 3;                 // 0..3  (64-col quarter of 256)
  const int bn   = blockIdx.x & 7;          // bid%8 = XCD -> B panel L2-local
  const int bm   = blockIdx.x >> 3;         // 0..63
  const int a0r = bm * 128, h0 = bn * 256;

  f32x4 acc[4][4] = {};
  short8 af[4], bf[4];

  // ---- staging: linear LDS dest (tid*16), inverse-swizzled global source
  const int r0 = tid >> 2, s0 = tid & 3;    // r0 0..127
  const int swzB = (s0 ^ ((r0 >> 1) & 3)) * 16;        // R4 0-conflict form
  const char* Asrc  = (const char*)A + ((size_t)(a0r + r0) * D_M) * 2 + swzB;
  const char* Bsrc0 = (const char*)B + ((size_t)(h0 + r0) * D_M) * 2 + swzB;
  const char* Bsrc1 = Bsrc0 + (size_t)128 * D_M * 2;

#define STAGE(S, kt) { \
  gload_lds16(Asrc  + (size_t)(kt) * 64, lds + (S) * 8192 + tid * 16); \
  char* bd_ = lds + 24576 + (S) * 16384 + tid * 16; \
  gload_lds16(Bsrc0 + (size_t)(kt) * 64, bd_); \
  gload_lds16(Bsrc1 + (size_t)(kt) * 64, bd_ + 8192); }

  // ---- fragment read offsets (same involutive swizzle)
  const int rl  = lane & 15;
  const int rsw = (((lane >> 4) ^ ((rl >> 1) & 3))) * 16;
  const int Aro = (wm * 64 + rl) * 64 + rsw;            // + mf*1024 + S*8192
  const int Bro = 24576 + (wn * 64 + rl) * 64 + rsw;    // + nf*1024 + S*16384

#define TILE(S, SST, T) { \
  _Pragma("unroll") \
  for (int mf = 0; mf < 4; ++mf) \
    af[mf] = *(const short8*)(lds + (S) * 8192 + Aro + mf * 1024); \
  _Pragma("unroll") \
  for (int nf = 0; nf < 4; ++nf) \
    bf[nf] = *(const short8*)(lds + (S) * 16384 + Bro + nf * 1024); \
  if ((T) < GNT3 - 2) STAGE(SST, (T) + 2); \
  LGKM0(); SB0(); \
  __builtin_amdgcn_s_setprio(1); \
  _Pragma("unroll") \
  for (int mf = 0; mf < 4; ++mf) \
    _Pragma("unroll") \
    for (int nf = 0; nf < 4; ++nf) \
      acc[mf][nf] = __builtin_amdgcn_mfma_f32_16x16x32_bf16(af[mf], bf[nf], acc[mf][nf], 0, 0, 0); \
  __builtin_amdgcn_s_setprio(0); \
  if ((T) < GNT3 - 2)       { asm volatile("s_waitcnt vmcnt(3)" ::: "memory"); } \
  else if ((T) == GNT3 - 2) { asm volatile("s_waitcnt vmcnt(0)" ::: "memory"); } \
  if ((T) < GNT3 - 1) BARX(); }

  // ---- prologue: 2 tiles staged, tile 0 landed
  STAGE(0, 0); STAGE(1, 1);
  asm volatile("s_waitcnt vmcnt(3)" ::: "memory");
  BARX();

  // ---- K-loop: 3-slot ring, unroll by 3
  for (int tt = 0; tt < GNT3 - 2; tt += 3) {
    TILE(0, 2, tt);
    TILE(1, 0, tt + 1);
    TILE(2, 1, tt + 2);
  }
  TILE(0, 2, 30);
  TILE(1, 0, 31);

  // ---- epilogue: C row = (lane>>4)*4 + r (A side), col = lane&15 (B side)
  const int cl = lane & 15, rq = lane >> 4;
  #pragma unroll
  for (int nf = 0; nf < 4; ++nf) {
    const int h = h0 + wn * 64 + nf * 16 + cl;
    const float bv = bias[h];
    #pragma unroll
    for (int mf = 0; mf < 4; ++mf) {
      const int ar = a0r + wm * 64 + mf * 16 + rq * 4;
      #pragma unroll
      for (int r = 0; r < 4; ++r)
        out[(size_t)(ar + r) * D_H + h] = acc[mf][nf][r] + bv;
    }
  }
#undef STAGE
#undef TILE
}

extern "C" void kernel_launch(void* const* d_in, const int* in_sizes, int n_in,
                              void* d_out, int out_size, void* d_ws, size_t ws_size,
                              hipStream_t stream) {
  const float* x  = (const float*)d_in[0];
  const int*   t  = (const int*)d_in[1];
  const float* gm = (const float*)d_in[2];
  const float* W  = (const float*)d_in[3];
  const float* b  = (const float*)d_in[4];
  float* out = (float*)d_out;

  const size_t SZ_REG = (size_t)ALPHA * D_M * 2;   // 16 MB
  const size_t SZ_WB  = (size_t)D_H * D_M * 2;     //  4 MB

  if (ws_size >= 2 * SZ_REG + SZ_WB) {
    unsigned short* reg  = (unsigned short*)d_ws;
    unsigned short* regT = (unsigned short*)((char*)d_ws + SZ_REG);
    unsigned short* Wb   = (unsigned short*)((char*)d_ws + 2 * SZ_REG);
    impute_fill<<<D_M, 1024, 0, stream>>>(x, t, gm, reg, 0);
    wconv<<<(D_H * D_M) / 1024, 256, 0, stream>>>(W, Wb);
    transpose_bf<<<(ALPHA / 64) * (D_M / 64), 256, 0, stream>>>(reg, regT);
    gemm_bias<<<(ALPHA / 128) * (D_H / 256), 512, 0, stream>>>(regT, Wb, b, out);
  } else {
    unsigned short* regT = (unsigned short*)d_ws;
    unsigned short* Wb   = (unsigned short*)((char*)d_ws + SZ_REG);
    impute_fill<<<D_M, 1024, 0, stream>>>(x, t, gm, regT, 1);
    wconv<<<(D_H * D_M) / 1024, 256, 0, stream>>>(W, Wb);
    gemm_bias<<<(ALPHA / 128) * (D_H / 256), 512, 0, stream>>>(regT, Wb, b, out);
  }
}